// Round 2
// baseline (751.081 us; speedup 1.0000x reference)
//
#include <hip/hip_runtime.h>
#include <math.h>

#define N_NODES 100000
#define N_EDGES 1600000
#define NODE_F  64
#define IN_DIM  160          // 2*64 + 32
#define N_TILES 25000        // N_EDGES / 64
#define ZSTRIDE 168          // bf16 elems per z-row in LDS (336 B, 16B-aligned)
#define EDGE_GRID 1536       // 6 blocks/CU

#define SCAN_BLOCKS 391      // ceil(100000/256)
#define E_BLOCKS    6250     // N_EDGES/256

typedef __attribute__((ext_vector_type(8))) short short8;   // 8 bf16 = 4 VGPRs
typedef __attribute__((ext_vector_type(4))) float f32x4;

// round-to-nearest-even f32 -> bf16 bits (scalar; used only in W staging)
static __device__ inline unsigned short f2bf(float f) {
    union { float f; unsigned u; } v; v.f = f;
    unsigned r = v.u + 0x7fffu + ((v.u >> 16) & 1u);
    return (unsigned short)(r >> 16);
}

// RNE-round two f32 and pack their high halves into one dword.
static __device__ inline unsigned pack2(float lo, float hi) {
    union { float f; unsigned u; } a, b; a.f = lo; b.f = hi;
    const unsigned ra = a.u + 0x7fffu + ((a.u >> 16) & 1u);
    const unsigned rb = b.u + 0x7fffu + ((b.u >> 16) & 1u);
    return __builtin_amdgcn_perm(rb, ra, 0x07060302u);
}

// LDS row for edge e (0..63) within a tile, chosen so that the C-tile's
// (mt, quad, r) row maps to edge quad*16 + mt*4 + r: each quad's epilogue
// walk over (mt,r) then visits 16 CONSECUTIVE sorted edges -> carry-chain
// merge of equal-source runs.
static __device__ inline int permrow(int e) {
    return ((e >> 2) & 3) * 16 + (e >> 4) * 4 + (e & 3);
}

// ===========================================================================
// Counting sort of edges by source: hist -> scan (3-level) -> scatter.
// ===========================================================================
__global__ __launch_bounds__(256) void hist_kernel(
    const int* __restrict__ src, int* __restrict__ hist)
{
    const int e = blockIdx.x * 256 + threadIdx.x;
    if (e < N_EDGES) atomicAdd(&hist[src[e]], 1);
}

__global__ __launch_bounds__(256) void scan1_kernel(
    const int* __restrict__ hist, int* __restrict__ partial)
{
    __shared__ int lds[256];
    const int tid = threadIdx.x;
    const int idx = blockIdx.x * 256 + tid;
    lds[tid] = (idx < N_NODES) ? hist[idx] : 0;
    __syncthreads();
    for (int s = 128; s > 0; s >>= 1) {
        if (tid < s) lds[tid] += lds[tid + s];
        __syncthreads();
    }
    if (tid == 0) partial[blockIdx.x] = lds[0];
}

__global__ __launch_bounds__(512) void scan2_kernel(int* __restrict__ partial)
{
    __shared__ int lds[512];
    const int tid = threadIdx.x;
    const int v = (tid < SCAN_BLOCKS) ? partial[tid] : 0;
    lds[tid] = v;
    __syncthreads();
    for (int off = 1; off < 512; off <<= 1) {
        const int t = (tid >= off) ? lds[tid - off] : 0;
        __syncthreads();
        lds[tid] += t;
        __syncthreads();
    }
    if (tid < SCAN_BLOCKS) partial[tid] = lds[tid] - v;   // exclusive
}

__global__ __launch_bounds__(256) void scan3_kernel(
    int* __restrict__ hist, const int* __restrict__ partial)
{
    __shared__ int lds[256];
    const int tid = threadIdx.x;
    const int idx = blockIdx.x * 256 + tid;
    const int v = (idx < N_NODES) ? hist[idx] : 0;
    lds[tid] = v;
    __syncthreads();
    for (int off = 1; off < 256; off <<= 1) {
        const int t = (tid >= off) ? lds[tid - off] : 0;
        __syncthreads();
        lds[tid] += t;
        __syncthreads();
    }
    if (idx < N_NODES) hist[idx] = lds[tid] - v + partial[blockIdx.x];
}

__global__ __launch_bounds__(256) void scatter_kernel(
    const int* __restrict__ src, const int* __restrict__ tgt,
    int* __restrict__ cursor,
    int* __restrict__ sSrc, int* __restrict__ sTgt, int* __restrict__ perm)
{
    const int e = blockIdx.x * 256 + threadIdx.x;
    if (e >= N_EDGES) return;
    const int s = src[e];
    const int pos = atomicAdd(&cursor[s], 1);
    sSrc[pos] = s;
    sTgt[pos] = tgt[e];
    perm[pos] = e;
}

// ===========================================================================
// Phase 1 (sorted): gather -> bf16 z-tile -> MFMA gated MLP -> run-merged
// atomic scatter. Sources sorted ascending: each quad's (mt,r) walk covers 16
// consecutive edges; equal-source runs merge in a register carry chain.
// ===========================================================================
__global__ __launch_bounds__(256, 6) void edge_kernel_sorted(
    const float* __restrict__ node_attrs,
    const int*   __restrict__ sSrc,
    const int*   __restrict__ sTgt,
    const int*   __restrict__ perm,
    const float* __restrict__ edge_attrs,
    const float* __restrict__ W_f, const float* __restrict__ b_f,
    const float* __restrict__ W_s, const float* __restrict__ b_s,
    float* __restrict__ msg)
{
    __shared__ __align__(16) short sbuf[64 * ZSTRIDE];   // 21504 B
    unsigned* sbuf32 = (unsigned*)sbuf;

    const int tid  = threadIdx.x;
    const int wave = tid >> 6;
    const int lane = tid & 63;
    const int quad = lane >> 4;       // 0..3
    const int l15  = lane & 15;

    // ---- Stage W_f then W_s transposed to LDS, pull B-fragments to registers.
    short8 bF[5], bS[5];
#pragma unroll
    for (int mat = 0; mat < 2; ++mat) {
        const float* W = mat ? W_s : W_f;
        __syncthreads();
        for (int idx = tid; idx < IN_DIM * 64; idx += 256) {
            const int k = idx >> 6, n = idx & 63;
            sbuf[n * ZSTRIDE + k] = (short)f2bf(W[idx]);
        }
        __syncthreads();
#pragma unroll
        for (int kc = 0; kc < 5; ++kc) {
            const short8 b = *(const short8*)&sbuf[(16 * wave + l15) * ZSTRIDE + kc * 32 + quad * 8];
            if (mat) bS[kc] = b; else bF[kc] = b;
        }
    }

    const float bias_f = b_f[16 * wave + l15];
    const float bias_s = b_s[16 * wave + l15];
    float* const msgf  = msg + 16 * wave + l15;   // per-lane feature column

    // Prefetch first tile's indices.
    int srcv = sSrc[blockIdx.x * 64 + lane];
    int tgtv = sTgt[blockIdx.x * 64 + lane];
    int prmv = perm[blockIdx.x * 64 + lane];

    for (int t = blockIdx.x; t < N_TILES; t += EDGE_GRID) {
        __syncthreads();   // protect sbuf from previous iteration's readers

        // Prefetch next tile's indices (overlaps the gather/stage section).
        const int tn = t + EDGE_GRID;
        int nsrc = 0, ntgt = 0, nprm = 0;
        if (tn < N_TILES) {
            nsrc = sSrc[tn * 64 + lane];
            ntgt = sTgt[tn * 64 + lane];
            nprm = perm[tn * 64 + lane];
        }

        // ---- Node rows (f32 -> bf16): wave w stages edges [16w,16w+16).
        // LDS row is permrow(edge): MFMA C-row (mt,quad,r) <-> edge q*16+mt*4+r.
#pragma unroll
        for (int i = 0; i < 8; ++i) {
            const int el   = i * 2 + (quad >> 1);
            const int half = quad & 1;
            const int sl   = 16 * wave + el;       // edge within tile
            const int ns   = __shfl(srcv, sl);
            const int nt   = __shfl(tgtv, sl);
            const int node = half ? nt : ns;
            const int row  = permrow(sl);
            const float4 v = *(const float4*)&node_attrs[node * 64 + l15 * 4];
            uint2 o; o.x = pack2(v.x, v.y); o.y = pack2(v.z, v.w);
            *(uint2*)&sbuf32[row * (ZSTRIDE / 2) + half * 32 + l15 * 2] = o;
        }
        // ---- Edge attrs (f32 -> bf16): gathered 128B rows via perm.
#pragma unroll
        for (int i = 0; i < 2; ++i) {
            const int p  = i * 256 + tid;       // 0..511
            const int el = p >> 3, g = p & 7;
            const int pe = __shfl(prmv, el);    // original edge id
            const int row = permrow(el);
            const float4 v = *(const float4*)&edge_attrs[(size_t)pe * 32 + g * 4];
            uint2 o; o.x = pack2(v.x, v.y); o.y = pack2(v.z, v.w);
            *(uint2*)&sbuf32[row * (ZSTRIDE / 2) + 64 + g * 2] = o;
        }
        __syncthreads();

        // ---- MFMA: 4 m-tiles x 5 k-chunks x 2 matrices, carry-chain epilogue.
        int lastn = -1;
        float carry = 0.0f;
#pragma unroll
        for (int mt = 0; mt < 4; ++mt) {
            f32x4 accF = {0.f, 0.f, 0.f, 0.f};
            f32x4 accS = {0.f, 0.f, 0.f, 0.f};
#pragma unroll
            for (int kc = 0; kc < 5; ++kc) {
                const short8 a = *(const short8*)&sbuf[(mt * 16 + l15) * ZSTRIDE + kc * 32 + quad * 8];
                accF = __builtin_amdgcn_mfma_f32_16x16x32_bf16(a, bF[kc], accF, 0, 0, 0);
                accS = __builtin_amdgcn_mfma_f32_16x16x32_bf16(a, bS[kc], accS, 0, 0, 0);
            }
            // C/D row (quad*4+r within mt) holds edge quad*16 + mt*4 + r.
#pragma unroll
            for (int r = 0; r < 4; ++r) {
                const float xf = accF[r] + bias_f;
                const float xs = accS[r] + bias_s;
                const float sig = __builtin_amdgcn_rcpf(1.0f + __expf(-xf));
                const float sp  = fmaxf(xs, 0.0f) + __logf(1.0f + __expf(-fabsf(xs)));
                const float h   = sig * sp;
                const int e     = quad * 16 + mt * 4 + r;   // sorted edge in tile
                const int n     = __shfl(srcv, e);          // quad-uniform
                if (n == lastn) {
                    carry += h;
                } else {
                    if (lastn >= 0) atomicAdd(&msgf[lastn * 64], carry);
                    lastn = n;
                    carry = h;
                }
            }
        }
        atomicAdd(&msgf[lastn * 64], carry);   // flush last run of the tile

        srcv = nsrc;
        tgtv = ntgt;
        prmv = nprm;
    }
}

// ===========================================================================
// Fallback phase 1 (unsorted, atomic-per-feature) for small workspaces.
// ===========================================================================
__global__ __launch_bounds__(256, 6) void edge_kernel(
    const float* __restrict__ node_attrs,
    const int*   __restrict__ edge_src,
    const int*   __restrict__ edge_tgt,
    const float* __restrict__ edge_attrs,
    const float* __restrict__ W_f, const float* __restrict__ b_f,
    const float* __restrict__ W_s, const float* __restrict__ b_s,
    float* __restrict__ msg)
{
    __shared__ __align__(16) short sbuf[64 * ZSTRIDE];
    unsigned* sbuf32 = (unsigned*)sbuf;

    const int tid  = threadIdx.x;
    const int wave = tid >> 6;
    const int lane = tid & 63;
    const int quad = lane >> 4;
    const int l15  = lane & 15;

    short8 bF[5], bS[5];
#pragma unroll
    for (int mat = 0; mat < 2; ++mat) {
        const float* W = mat ? W_s : W_f;
        __syncthreads();
        for (int idx = tid; idx < IN_DIM * 64; idx += 256) {
            const int k = idx >> 6, n = idx & 63;
            sbuf[n * ZSTRIDE + k] = (short)f2bf(W[idx]);
        }
        __syncthreads();
#pragma unroll
        for (int kc = 0; kc < 5; ++kc) {
            const short8 b = *(const short8*)&sbuf[(16 * wave + l15) * ZSTRIDE + kc * 32 + quad * 8];
            if (mat) bS[kc] = b; else bF[kc] = b;
        }
    }

    const float bias_f = b_f[16 * wave + l15];
    const float bias_s = b_s[16 * wave + l15];
    float* const msgf  = msg + 16 * wave + l15;

    int srcv = edge_src[blockIdx.x * 64 + lane];
    int tgtv = edge_tgt[blockIdx.x * 64 + lane];

    for (int t = blockIdx.x; t < N_TILES; t += EDGE_GRID) {
        const int e0 = t * 64;
        __syncthreads();
#pragma unroll
        for (int i = 0; i < 8; ++i) {
            const int el   = i * 2 + (quad >> 1);
            const int half = quad & 1;
            const int sl   = 16 * wave + el;
            const int ns   = __shfl(srcv, sl);
            const int nt   = __shfl(tgtv, sl);
            const int node = half ? nt : ns;
            const float4 v = *(const float4*)&node_attrs[node * 64 + l15 * 4];
            uint2 o; o.x = pack2(v.x, v.y); o.y = pack2(v.z, v.w);
            *(uint2*)&sbuf32[sl * (ZSTRIDE / 2) + half * 32 + l15 * 2] = o;
        }
#pragma unroll
        for (int i = 0; i < 2; ++i) {
            const int p  = i * 256 + tid;
            const int el = p >> 3, g = p & 7;
            const float4 v = *(const float4*)&edge_attrs[(size_t)(e0 + el) * 32 + g * 4];
            uint2 o; o.x = pack2(v.x, v.y); o.y = pack2(v.z, v.w);
            *(uint2*)&sbuf32[el * (ZSTRIDE / 2) + 64 + g * 2] = o;
        }
        const int tn = t + EDGE_GRID;
        int nsrc = 0, ntgt = 0;
        if (tn < N_TILES) {
            nsrc = edge_src[tn * 64 + lane];
            ntgt = edge_tgt[tn * 64 + lane];
        }
        __syncthreads();
#pragma unroll
        for (int mt = 0; mt < 4; ++mt) {
            f32x4 accF = {0.f, 0.f, 0.f, 0.f};
            f32x4 accS = {0.f, 0.f, 0.f, 0.f};
#pragma unroll
            for (int kc = 0; kc < 5; ++kc) {
                const short8 a = *(const short8*)&sbuf[(mt * 16 + l15) * ZSTRIDE + kc * 32 + quad * 8];
                accF = __builtin_amdgcn_mfma_f32_16x16x32_bf16(a, bF[kc], accF, 0, 0, 0);
                accS = __builtin_amdgcn_mfma_f32_16x16x32_bf16(a, bS[kc], accS, 0, 0, 0);
            }
#pragma unroll
            for (int r = 0; r < 4; ++r) {
                const float xf = accF[r] + bias_f;
                const float xs = accS[r] + bias_s;
                const float sig = __builtin_amdgcn_rcpf(1.0f + __expf(-xf));
                const float sp  = fmaxf(xs, 0.0f) + __logf(1.0f + __expf(-fabsf(xs)));
                const float h   = sig * sp;
                const int sl    = mt * 16 + quad * 4 + r;
                const int node  = __shfl(srcv, sl);
                atomicAdd(&msgf[node * 64], h);
            }
        }
        srcv = nsrc;
        tgtv = ntgt;
    }
}

// ---------------------------------------------------------------------------
// Phase 2: per-feature sum / sumsq over nodes (round-0 version).
// ---------------------------------------------------------------------------
#define STATS_BLOCKS 400
__global__ __launch_bounds__(256) void stats_kernel(
    const float* __restrict__ msg, float* __restrict__ stats)
{
    const int tid = threadIdx.x;
    const int f = tid & 63;
    const int g = tid >> 6;
    float s = 0.0f, q = 0.0f;
    for (int r = blockIdx.x * 4 + g; r < N_NODES; r += STATS_BLOCKS * 4) {
        const float v = msg[r * 64 + f];
        s += v;
        q = fmaf(v, v, q);
    }
    __shared__ float rs[4][64];
    __shared__ float rq[4][64];
    rs[g][f] = s;
    rq[g][f] = q;
    __syncthreads();
    if (tid < 64) {
        const float ss = rs[0][f] + rs[1][f] + rs[2][f] + rs[3][f];
        const float qq = rq[0][f] + rq[1][f] + rq[2][f] + rq[3][f];
        atomicAdd(&stats[f], ss);
        atomicAdd(&stats[64 + f], qq);
    }
}

// ---------------------------------------------------------------------------
// Phase 3: in-place BN (training stats, biased var) + residual.
// ---------------------------------------------------------------------------
__global__ __launch_bounds__(256) void norm_kernel(
    const float* __restrict__ node_attrs,
    const float* __restrict__ stats,
    const float* __restrict__ gamma,
    const float* __restrict__ beta,
    float* __restrict__ out)
{
    const int i = blockIdx.x * blockDim.x + threadIdx.x;
    const int idx = i * 4;
    if (idx >= N_NODES * 64) return;
    const int f = idx & 63;
    const float inv_n = 1.0f / (float)N_NODES;

    const float4 m4 = *(const float4*)&out[idx];
    const float4 x4 = *(const float4*)&node_attrs[idx];

    float mean[4], rstd[4], gm[4], bt[4];
#pragma unroll
    for (int j = 0; j < 4; ++j) {
        mean[j] = stats[f + j] * inv_n;
        const float var = stats[64 + f + j] * inv_n - mean[j] * mean[j];
        rstd[j] = rsqrtf(var + 1e-5f);
        gm[j] = gamma[f + j];
        bt[j] = beta[f + j];
    }
    float4 o;
    o.x = x4.x + (m4.x - mean[0]) * rstd[0] * gm[0] + bt[0];
    o.y = x4.y + (m4.y - mean[1]) * rstd[1] * gm[1] + bt[1];
    o.z = x4.z + (m4.z - mean[2]) * rstd[2] * gm[2] + bt[2];
    o.w = x4.w + (m4.w - mean[3]) * rstd[3] * gm[3] + bt[3];
    *(float4*)&out[idx] = o;
}

extern "C" void kernel_launch(void* const* d_in, const int* in_sizes, int n_in,
                              void* d_out, int out_size, void* d_ws, size_t ws_size,
                              hipStream_t stream)
{
    const float* node_attrs = (const float*)d_in[0];
    const int*   edge_index = (const int*)d_in[1];   // [2, E] int32
    const float* edge_attrs = (const float*)d_in[2];
    const float* W_f   = (const float*)d_in[3];
    const float* b_f   = (const float*)d_in[4];
    const float* W_s   = (const float*)d_in[5];
    const float* b_s   = (const float*)d_in[6];
    const float* gamma = (const float*)d_in[7];
    const float* beta  = (const float*)d_in[8];

    float* out   = (float*)d_out;          // doubles as the msg accumulator
    float* stats = (float*)d_ws;           // 128 floats

    const int* edge_src = edge_index;
    const int* edge_tgt = edge_index + N_EDGES;

    // Workspace layout (bytes):
    //   [0,512)            stats
    //   [1024,3072)        scan partials (512 ints)
    //   [4096,404096)      hist/offsets/cursor (100000 ints)
    //   [404224,...)       perm, sSrc, sTgt (1.6M ints each)
    char* wsb = (char*)d_ws;
    int* partial = (int*)(wsb + 1024);
    int* hist    = (int*)(wsb + 4096);
    int* perm    = (int*)(wsb + 404224);
    int* sSrc    = perm + N_EDGES;
    int* sTgt    = sSrc + N_EDGES;
    const size_t WS_NEED = 404224 + 3ull * N_EDGES * 4;   // ~19.6 MB

    hipMemsetAsync(out, 0, (size_t)N_NODES * NODE_F * sizeof(float), stream);
    hipMemsetAsync(stats, 0, 128 * sizeof(float), stream);

    if (ws_size >= WS_NEED) {
        hipMemsetAsync(hist, 0, (size_t)N_NODES * sizeof(int), stream);
        hist_kernel<<<E_BLOCKS, 256, 0, stream>>>(edge_src, hist);
        scan1_kernel<<<SCAN_BLOCKS, 256, 0, stream>>>(hist, partial);
        scan2_kernel<<<1, 512, 0, stream>>>(partial);
        scan3_kernel<<<SCAN_BLOCKS, 256, 0, stream>>>(hist, partial);
        scatter_kernel<<<E_BLOCKS, 256, 0, stream>>>(
            edge_src, edge_tgt, hist, sSrc, sTgt, perm);
        edge_kernel_sorted<<<EDGE_GRID, 256, 0, stream>>>(
            node_attrs, sSrc, sTgt, perm, edge_attrs, W_f, b_f, W_s, b_s, out);
    } else {
        edge_kernel<<<EDGE_GRID, 256, 0, stream>>>(
            node_attrs, edge_src, edge_tgt, edge_attrs, W_f, b_f, W_s, b_s, out);
    }

    stats_kernel<<<STATS_BLOCKS, 256, 0, stream>>>(out, stats);

    norm_kernel<<<(N_NODES * NODE_F / 4 + 255) / 256, 256, 0, stream>>>(
        node_attrs, stats, gamma, beta, out);
}